// Round 7
// baseline (434.188 us; speedup 1.0000x reference)
//
#include <hip/hip_runtime.h>

// AgentGnn: 2x CGConv(D=64) on 1024 disjoint fully-connected 32-node blocks.
// Round 7: latency-bound fix. Grid 2048 (half-sample blocks: 16 dst x 64ch,
// 4 ch/thread), LDS = single 16.9KB G buffer (no x/edge staging -> 8 blocks/CU
// = all 32 wave slots), shfl-based stats reduce. Math unchanged from round 6:
// z@W split, exp2-domain gate (inputs scaled by log2e, softplus ln2 dropped,
// BN eps scaled by L2E^2 -> exactly equivalent in real arithmetic).

#define NSAMP 1024
#define AG 32
#define DD 64
#define EPB 992          // edges per sample = 32*31
#define NN 32768
#define R1S 132          // padded row stride (row-spread across banks)

typedef float f4 __attribute__((ext_vector_type(4)));
typedef float f2 __attribute__((ext_vector_type(2)));

#define L2E 1.44269504088896340736f
// rsqrt(c^2 v + c^2 eps)*c == rsqrt(v+eps), c = L2E
#define BN_EPS_SCALED (1e-5 * (double)L2E * (double)L2E)

// acc += sigmoid(mf)*softplus(ms)/ln2; mf,ms pre-scaled by log2e.
// __builtin_amdgcn_logf == v_log_f32 == log2: log2(1+2^ms)=max(ms,0)+log2(1+2^-|ms|).
__device__ __forceinline__ void gacc(f4& acc, const f4 mf, const f4 ms) {
#pragma unroll
  for (int k = 0; k < 4; ++k) {
    float sig = __builtin_amdgcn_rcpf(1.0f + __builtin_amdgcn_exp2f(-mf[k]));
    float sp  = fmaxf(ms[k], 0.0f)
              + __builtin_amdgcn_logf(1.0f + __builtin_amdgcn_exp2f(-fabsf(ms[k])));
    acc[k] += sig * sp;   // v_fmac
  }
}

// G half-pass reading node features from GLOBAL (L2-hot, broadcast addrs).
// SRC=0: W rows [0:64] (dst) + bias; computes own-half rows rbase..rbase+16,
//        stored at local rows 0..16. SRC=1: W rows [64:128] (src), all 32 rows.
// Output scaled by L2E.
template <int SRC>
__device__ __forceinline__ void gpass(const float* __restrict__ Wf,
                                      const float* __restrict__ bfv,
                                      const float* __restrict__ Ws,
                                      const float* __restrict__ bsv,
                                      const float* __restrict__ xs,  // sample base
                                      float* R1, int t, int rbase) {
  const int tx = t & 31, ty = t >> 5;          // 8 row groups
  const int q = tx >> 4;                        // 0: f-gate, 1: s-gate
  const int cc0 = (tx & 15) * 4;
  const float* wbase = (q ? Ws : Wf) + SRC * (64 * 64) + cc0;
  constexpr int RPT = (SRC == 0) ? 2 : 4;       // rows per thread
  f4 acc[RPT];
  if constexpr (SRC == 0) {
    const float* bv = q ? bsv : bfv;
    f4 b = *(const f4*)(bv + cc0);
#pragma unroll
    for (int r = 0; r < RPT; ++r) acc[r] = b;
  } else {
    f4 z = {0.f, 0.f, 0.f, 0.f};
#pragma unroll
    for (int r = 0; r < RPT; ++r) acc[r] = z;
  }
#pragma unroll 4
  for (int k4 = 0; k4 < 16; ++k4) {
    const float* wp = wbase + k4 * 256;         // 4 weight rows, coalesced f4
    f4 w0 = *(const f4*)(wp);
    f4 w1 = *(const f4*)(wp + 64);
    f4 w2 = *(const f4*)(wp + 128);
    f4 w3 = *(const f4*)(wp + 192);
#pragma unroll
    for (int r = 0; r < RPT; ++r) {
      const int row = (SRC == 0) ? (rbase + ty * RPT + r) : (ty * RPT + r);
      f4 xv = *(const f4*)(xs + row * 64 + k4 * 4);   // broadcast across lanes
      acc[r] += xv.x * w0 + xv.y * w1 + xv.z * w2 + xv.w * w3;
    }
  }
#pragma unroll
  for (int r = 0; r < RPT; ++r)
    *(f4*)&R1[(ty * RPT + r) * R1S + q * 64 + cc0] = acc[r] * L2E;
}

// One layer's message+aggregate+BN-stats for a half-sample block.
// xs = global node-feature sample base (x or h). agg/stats written.
__device__ __forceinline__ void layer_body(
    int t, int s, int rbase,
    const float* __restrict__ xs, const float* __restrict__ ea,
    const float* __restrict__ Wf, const float* __restrict__ bfv,
    const float* __restrict__ Ws, const float* __restrict__ bsv,
    float* R1, float* __restrict__ agg, double* __restrict__ stats)
{
  gpass<0>(Wf, bfv, Ws, bsv, xs, R1, t, rbase);         // own-half [Af|As]
  __syncthreads();
  const int il = t >> 4, c0 = (t & 15) * 4;
  f4 af  = *(const f4*)&R1[il * R1S + c0];
  f4 as_ = *(const f4*)&R1[il * R1S + 64 + c0];
  __syncthreads();                                       // reads done
  gpass<1>(Wf, bfv, Ws, bsv, xs, R1, t, 0);              // all-32 [Bf|Bs]

  f4 wf0 = *(const f4*)(Wf + 128 * 64 + c0) * L2E;       // edge-dim rows
  f4 wf1 = *(const f4*)(Wf + 129 * 64 + c0) * L2E;
  f4 ws0 = *(const f4*)(Ws + 128 * 64 + c0) * L2E;
  f4 ws1 = *(const f4*)(Ws + 129 * 64 + c0) * L2E;
  __syncthreads();                                       // pass1 visible

  const int i = rbase + il;                              // own dst node
  const f2* ep = (const f2*)ea + (size_t)s * EPB;        // edges from L2
  f4 acc = {0.f, 0.f, 0.f, 0.f};
  for (int jj = 0; jj < 31; ++jj) {                      // skip diagonal
    const int ge = (jj >= i) ? 1 : 0;
    const int j  = jj + ge;
    const int e  = j * 31 + i - 1 + ge;                  // src-major edge id
    f2 eav = ep[e];
    f4 bf_ = *(const f4*)&R1[j * R1S + c0];              // j uniform: broadcast
    f4 bs_ = *(const f4*)&R1[j * R1S + 64 + c0];
    f4 mf = af  + bf_ + eav.x * wf0 + eav.y * wf1;
    f4 ms = as_ + bs_ + eav.x * ws0 + eav.y * ws1;
    gacc(acc, mf, ms);
  }
  *(f4*)(agg + ((size_t)s * AG + i) * DD + c0) = acc;

  // BN stats: shfl-reduce the 4 same-channel lanes per wave, then LDS, then global.
  f4 s1 = acc, sq = acc * acc;
#pragma unroll
  for (int k = 0; k < 4; ++k) {
    s1[k] += __shfl_xor(s1[k], 16); sq[k] += __shfl_xor(sq[k], 16);
    s1[k] += __shfl_xor(s1[k], 32); sq[k] += __shfl_xor(sq[k], 32);
  }
  __syncthreads();                                       // loop reads of R1 done
  if (t < 128) R1[t] = 0.0f;
  __syncthreads();
  if ((t & 63) < 16) {
#pragma unroll
    for (int k = 0; k < 4; ++k) {
      atomicAdd(&R1[c0 + k],      s1[k]);
      atomicAdd(&R1[64 + c0 + k], sq[k]);
    }
  }
  __syncthreads();
  if (t < 128) atomicAdd(&stats[t], (double)R1[t]);
}

// K1: layer-1 edge phase (half-sample blocks, grid 2048).
__global__ __launch_bounds__(256, 8) void k_edge1(
    const float* __restrict__ x, const float* __restrict__ ea,
    const float* __restrict__ Wf, const float* __restrict__ bfv,
    const float* __restrict__ Ws, const float* __restrict__ bsv,
    float* __restrict__ agg, double* __restrict__ stats)
{
  __shared__ __align__(16) float R1[32 * R1S];
  const int t = threadIdx.x, b = blockIdx.x;
  const int s = b >> 1, rbase = (b & 1) * 16;
  layer_body(t, s, rbase, x + (size_t)s * AG * DD, ea,
             Wf, bfv, Ws, bsv, R1, agg, stats);
}

// K2: BN1-apply+residual+relu -> h for ALL 32 rows of the sample (duplicate
// identical writes across the 2 half-blocks -> race-safe), then layer-2 edge
// reading h from global. agg2 is a SEPARATE buffer (sibling block reads agg1).
__global__ __launch_bounds__(256, 8) void k_edge2(
    const float* __restrict__ x, const float* __restrict__ ea,
    const float* __restrict__ Wf, const float* __restrict__ bfv,
    const float* __restrict__ Ws, const float* __restrict__ bsv,
    const double* __restrict__ stats1, const float* __restrict__ gmv,
    const float* __restrict__ btv, float* __restrict__ hout,
    const float* __restrict__ agg1, float* __restrict__ agg2,
    double* __restrict__ stats2)
{
  __shared__ __align__(16) float R1[32 * R1S];
  const int t = threadIdx.x, b = blockIdx.x;
  const int s = b >> 1, rbase = (b & 1) * 16;

  if (t < 64) {                     // BN1 scale/shift (redundant per block)
    double mu  = stats1[t] * (1.0 / NN);
    double var = stats1[64 + t] * (1.0 / NN) - mu * mu;
    float rs = (float)(1.0 / sqrt(var + BN_EPS_SCALED));
    float g  = gmv[t] * rs;
    R1[t]      = g;
    R1[64 + t] = btv[t] - (float)mu * g;
  }
  __syncthreads();
  {                                 // h = relu(BN1(agg1)+x), all 32 rows
    const int row = t >> 3, cc = (t & 7) * 8;
    const size_t base = ((size_t)s * AG + row) * DD + cc;
    f4 sc0 = *(const f4*)&R1[cc],      sc1 = *(const f4*)&R1[cc + 4];
    f4 sh0 = *(const f4*)&R1[64 + cc], sh1 = *(const f4*)&R1[64 + cc + 4];
    f4 a0 = *(const f4*)(agg1 + base), a1 = *(const f4*)(agg1 + base + 4);
    f4 x0 = *(const f4*)(x + base),    x1 = *(const f4*)(x + base + 4);
    f4 h0 = a0 * sc0 + sh0 + x0;
    f4 h1 = a1 * sc1 + sh1 + x1;
#pragma unroll
    for (int k = 0; k < 4; ++k) { h0[k] = fmaxf(h0[k], 0.f); h1[k] = fmaxf(h1[k], 0.f); }
    *(f4*)(hout + base)     = h0;   // identical bytes from both half-blocks
    *(f4*)(hout + base + 4) = h1;
  }
  __syncthreads();                  // drains vmem (compiler waitcnt) + R1 reads
  layer_body(t, s, rbase, hout + (size_t)s * AG * DD, ea,
             Wf, bfv, Ws, bsv, R1, agg2, stats2);
}

// K3: out = relu(BN2(agg2) + h), in place on d_out (holds h).
__global__ __launch_bounds__(256) void k_norm(
    const float* __restrict__ agg, const double* __restrict__ stats,
    const float* __restrict__ gmv, const float* __restrict__ btv,
    float* __restrict__ outp)
{
  __shared__ __align__(16) float sc[DD];
  __shared__ __align__(16) float sh[DD];
  const int t = threadIdx.x;
  if (t < DD) {
    double mu  = stats[t] * (1.0 / NN);
    double var = stats[DD + t] * (1.0 / NN) - mu * mu;
    float rs = (float)(1.0 / sqrt(var + BN_EPS_SCALED));
    float g  = gmv[t] * rs;
    sc[t] = g;
    sh[t] = btv[t] - (float)mu * g;
  }
  __syncthreads();
  const int idx = blockIdx.x * 256 + t;          // f4 index
  const int c   = (idx * 4) & (DD - 1);
  f4 a = ((const f4*)agg)[idx];
  f4 h = ((const f4*)outp)[idx];
  f4 r = a * (*(const f4*)&sc[c]) + (*(const f4*)&sh[c]) + h;
#pragma unroll
  for (int k = 0; k < 4; ++k) r[k] = fmaxf(r[k], 0.0f);
  ((f4*)outp)[idx] = r;
}

extern "C" void kernel_launch(void* const* d_in, const int* in_sizes, int n_in,
                              void* d_out, int out_size, void* d_ws, size_t ws_size,
                              hipStream_t stream) {
  const float* x   = (const float*)d_in[0];
  // d_in[1] = edge_index: deterministic meshgrid structure, recomputed on device
  const float* ea  = (const float*)d_in[2];
  const float* Wf1 = (const float*)d_in[3];
  const float* bf1 = (const float*)d_in[4];
  const float* Ws1 = (const float*)d_in[5];
  const float* bs1 = (const float*)d_in[6];
  const float* gm1 = (const float*)d_in[7];
  const float* bt1 = (const float*)d_in[8];
  const float* Wf2 = (const float*)d_in[9];
  const float* bf2 = (const float*)d_in[10];
  const float* Ws2 = (const float*)d_in[11];
  const float* bs2 = (const float*)d_in[12];
  const float* gm2 = (const float*)d_in[13];
  const float* bt2 = (const float*)d_in[14];

  // ws layout: [0,2KB) stats (memset 0); agg1 @4KB (8MB); agg2 @4KB+8MB (8MB).
  // Requires ws_size >= ~16.8MB; agg2 must be separate from agg1 because each
  // K2 half-block reads the sibling half's agg1 rows in its prologue.
  double* stats = (double*)d_ws;
  float*  agg1  = (float*)((char*)d_ws + 4096);
  float*  agg2  = (float*)((char*)d_ws + 4096 + (size_t)NN * DD * 4);
  float*  outp  = (float*)d_out;                 // h after K2, out after K3

  hipMemsetAsync(d_ws, 0, 2048, stream);
  k_edge1<<<2 * NSAMP, 256, 0, stream>>>(x, ea, Wf1, bf1, Ws1, bs1, agg1, stats);
  k_edge2<<<2 * NSAMP, 256, 0, stream>>>(x, ea, Wf2, bf2, Ws2, bs2,
                                         stats, gm1, bt1, outp, agg1, agg2,
                                         stats + 128);
  k_norm<<<NN * DD / 4 / 256, 256, 0, stream>>>(agg2, stats + 128, gm2, bt2, outp);
}

// Round 9
// 328.473 us; speedup vs baseline: 1.3218x; 1.3218x over previous
//
#include <hip/hip_runtime.h>

// AgentGnn: 2x CGConv(D=64) on 1024 disjoint fully-connected 32-node blocks.
// Round 8 = round 7 structure with the spill fixed: __launch_bounds__(256,4).
// Round 7's (256,8) squeezed the allocator to 32 VGPRs -> ~560B/thread scratch
// -> 293MB of HBM writes per dispatch (vs 8MB of real stores) -> 434us.
// Structure: grid 2048 (half-sample blocks: 16 dst x 64ch, 4 ch/thread),
// LDS = single 16.9KB G buffer (no x/edge staging), shfl-based stats reduce.
// Math: z@W split, exp2-domain gate (inputs scaled by log2e, softplus ln2
// dropped, BN eps scaled by L2E^2 -> exactly equivalent in real arithmetic).

#define NSAMP 1024
#define AG 32
#define DD 64
#define EPB 992          // edges per sample = 32*31
#define NN 32768
#define R1S 132          // padded row stride (row-spread across banks)

typedef float f4 __attribute__((ext_vector_type(4)));
typedef float f2 __attribute__((ext_vector_type(2)));

#define L2E 1.44269504088896340736f
// rsqrt(c^2 v + c^2 eps)*c == rsqrt(v+eps), c = L2E
#define BN_EPS_SCALED (1e-5 * (double)L2E * (double)L2E)

// acc += sigmoid(mf)*softplus(ms)/ln2; mf,ms pre-scaled by log2e.
// __builtin_amdgcn_logf == v_log_f32 == log2: log2(1+2^ms)=max(ms,0)+log2(1+2^-|ms|).
__device__ __forceinline__ void gacc(f4& acc, const f4 mf, const f4 ms) {
#pragma unroll
  for (int k = 0; k < 4; ++k) {
    float sig = __builtin_amdgcn_rcpf(1.0f + __builtin_amdgcn_exp2f(-mf[k]));
    float sp  = fmaxf(ms[k], 0.0f)
              + __builtin_amdgcn_logf(1.0f + __builtin_amdgcn_exp2f(-fabsf(ms[k])));
    acc[k] += sig * sp;   // v_fmac
  }
}

// G half-pass reading node features from GLOBAL (L2-hot, broadcast addrs).
// SRC=0: W rows [0:64] (dst) + bias; computes own-half rows rbase..rbase+16,
//        stored at local rows 0..16. SRC=1: W rows [64:128] (src), all 32 rows.
// Output scaled by L2E.
template <int SRC>
__device__ __forceinline__ void gpass(const float* __restrict__ Wf,
                                      const float* __restrict__ bfv,
                                      const float* __restrict__ Ws,
                                      const float* __restrict__ bsv,
                                      const float* __restrict__ xs,  // sample base
                                      float* R1, int t, int rbase) {
  const int tx = t & 31, ty = t >> 5;          // 8 row groups
  const int q = tx >> 4;                        // 0: f-gate, 1: s-gate
  const int cc0 = (tx & 15) * 4;
  const float* wbase = (q ? Ws : Wf) + SRC * (64 * 64) + cc0;
  constexpr int RPT = (SRC == 0) ? 2 : 4;       // rows per thread
  f4 acc[RPT];
  if constexpr (SRC == 0) {
    const float* bv = q ? bsv : bfv;
    f4 b = *(const f4*)(bv + cc0);
#pragma unroll
    for (int r = 0; r < RPT; ++r) acc[r] = b;
  } else {
    f4 z = {0.f, 0.f, 0.f, 0.f};
#pragma unroll
    for (int r = 0; r < RPT; ++r) acc[r] = z;
  }
#pragma unroll 4
  for (int k4 = 0; k4 < 16; ++k4) {
    const float* wp = wbase + k4 * 256;         // 4 weight rows, coalesced f4
    f4 w0 = *(const f4*)(wp);
    f4 w1 = *(const f4*)(wp + 64);
    f4 w2 = *(const f4*)(wp + 128);
    f4 w3 = *(const f4*)(wp + 192);
#pragma unroll
    for (int r = 0; r < RPT; ++r) {
      const int row = (SRC == 0) ? (rbase + ty * RPT + r) : (ty * RPT + r);
      f4 xv = *(const f4*)(xs + row * 64 + k4 * 4);   // broadcast across lanes
      acc[r] += xv.x * w0 + xv.y * w1 + xv.z * w2 + xv.w * w3;
    }
  }
#pragma unroll
  for (int r = 0; r < RPT; ++r)
    *(f4*)&R1[(ty * RPT + r) * R1S + q * 64 + cc0] = acc[r] * L2E;
}

// One layer's message+aggregate+BN-stats for a half-sample block.
// xs = global node-feature sample base (x or h). agg/stats written.
__device__ __forceinline__ void layer_body(
    int t, int s, int rbase,
    const float* __restrict__ xs, const float* __restrict__ ea,
    const float* __restrict__ Wf, const float* __restrict__ bfv,
    const float* __restrict__ Ws, const float* __restrict__ bsv,
    float* R1, float* __restrict__ agg, double* __restrict__ stats)
{
  gpass<0>(Wf, bfv, Ws, bsv, xs, R1, t, rbase);         // own-half [Af|As]
  __syncthreads();
  const int il = t >> 4, c0 = (t & 15) * 4;
  f4 af  = *(const f4*)&R1[il * R1S + c0];
  f4 as_ = *(const f4*)&R1[il * R1S + 64 + c0];
  __syncthreads();                                       // reads done
  gpass<1>(Wf, bfv, Ws, bsv, xs, R1, t, 0);              // all-32 [Bf|Bs]

  f4 wf0 = *(const f4*)(Wf + 128 * 64 + c0) * L2E;       // edge-dim rows
  f4 wf1 = *(const f4*)(Wf + 129 * 64 + c0) * L2E;
  f4 ws0 = *(const f4*)(Ws + 128 * 64 + c0) * L2E;
  f4 ws1 = *(const f4*)(Ws + 129 * 64 + c0) * L2E;
  __syncthreads();                                       // pass1 visible

  const int i = rbase + il;                              // own dst node
  const f2* ep = (const f2*)ea + (size_t)s * EPB;        // edges from L2
  f4 acc = {0.f, 0.f, 0.f, 0.f};
  for (int jj = 0; jj < 31; ++jj) {                      // skip diagonal
    const int ge = (jj >= i) ? 1 : 0;
    const int j  = jj + ge;
    const int e  = j * 31 + i - 1 + ge;                  // src-major edge id
    f2 eav = ep[e];
    f4 bf_ = *(const f4*)&R1[j * R1S + c0];              // j uniform: broadcast
    f4 bs_ = *(const f4*)&R1[j * R1S + 64 + c0];
    f4 mf = af  + bf_ + eav.x * wf0 + eav.y * wf1;
    f4 ms = as_ + bs_ + eav.x * ws0 + eav.y * ws1;
    gacc(acc, mf, ms);
  }
  *(f4*)(agg + ((size_t)s * AG + i) * DD + c0) = acc;

  // BN stats: shfl-reduce the 4 same-channel lanes per wave, then LDS, then global.
  f4 s1 = acc, sq = acc * acc;
#pragma unroll
  for (int k = 0; k < 4; ++k) {
    s1[k] += __shfl_xor(s1[k], 16); sq[k] += __shfl_xor(sq[k], 16);
    s1[k] += __shfl_xor(s1[k], 32); sq[k] += __shfl_xor(sq[k], 32);
  }
  __syncthreads();                                       // loop reads of R1 done
  if (t < 128) R1[t] = 0.0f;
  __syncthreads();
  if ((t & 63) < 16) {
#pragma unroll
    for (int k = 0; k < 4; ++k) {
      atomicAdd(&R1[c0 + k],      s1[k]);
      atomicAdd(&R1[64 + c0 + k], sq[k]);
    }
  }
  __syncthreads();
  if (t < 128) atomicAdd(&stats[t], (double)R1[t]);
}

// K1: layer-1 edge phase (half-sample blocks, grid 2048).
// launch_bounds (256,4): 128-reg budget. (256,8) starved the allocator to
// 32 VGPRs -> ~560B/thread scratch -> 293MB HBM writes (round-7 regression).
__global__ __launch_bounds__(256, 4) void k_edge1(
    const float* __restrict__ x, const float* __restrict__ ea,
    const float* __restrict__ Wf, const float* __restrict__ bfv,
    const float* __restrict__ Ws, const float* __restrict__ bsv,
    float* __restrict__ agg, double* __restrict__ stats)
{
  __shared__ __align__(16) float R1[32 * R1S];
  const int t = threadIdx.x, b = blockIdx.x;
  const int s = b >> 1, rbase = (b & 1) * 16;
  layer_body(t, s, rbase, x + (size_t)s * AG * DD, ea,
             Wf, bfv, Ws, bsv, R1, agg, stats);
}

// K2: BN1-apply+residual+relu -> h for ALL 32 rows of the sample (duplicate
// identical writes across the 2 half-blocks -> race-safe), then layer-2 edge
// reading h from global. agg2 is a SEPARATE buffer (sibling block reads agg1).
__global__ __launch_bounds__(256, 4) void k_edge2(
    const float* __restrict__ x, const float* __restrict__ ea,
    const float* __restrict__ Wf, const float* __restrict__ bfv,
    const float* __restrict__ Ws, const float* __restrict__ bsv,
    const double* __restrict__ stats1, const float* __restrict__ gmv,
    const float* __restrict__ btv, float* __restrict__ hout,
    const float* __restrict__ agg1, float* __restrict__ agg2,
    double* __restrict__ stats2)
{
  __shared__ __align__(16) float R1[32 * R1S];
  const int t = threadIdx.x, b = blockIdx.x;
  const int s = b >> 1, rbase = (b & 1) * 16;

  if (t < 64) {                     // BN1 scale/shift (redundant per block)
    double mu  = stats1[t] * (1.0 / NN);
    double var = stats1[64 + t] * (1.0 / NN) - mu * mu;
    float rs = (float)(1.0 / sqrt(var + BN_EPS_SCALED));
    float g  = gmv[t] * rs;
    R1[t]      = g;
    R1[64 + t] = btv[t] - (float)mu * g;
  }
  __syncthreads();
  {                                 // h = relu(BN1(agg1)+x), all 32 rows
    const int row = t >> 3, cc = (t & 7) * 8;
    const size_t base = ((size_t)s * AG + row) * DD + cc;
    f4 sc0 = *(const f4*)&R1[cc],      sc1 = *(const f4*)&R1[cc + 4];
    f4 sh0 = *(const f4*)&R1[64 + cc], sh1 = *(const f4*)&R1[64 + cc + 4];
    f4 a0 = *(const f4*)(agg1 + base), a1 = *(const f4*)(agg1 + base + 4);
    f4 x0 = *(const f4*)(x + base),    x1 = *(const f4*)(x + base + 4);
    f4 h0 = a0 * sc0 + sh0 + x0;
    f4 h1 = a1 * sc1 + sh1 + x1;
#pragma unroll
    for (int k = 0; k < 4; ++k) { h0[k] = fmaxf(h0[k], 0.f); h1[k] = fmaxf(h1[k], 0.f); }
    *(f4*)(hout + base)     = h0;   // identical bytes from both half-blocks
    *(f4*)(hout + base + 4) = h1;
  }
  __syncthreads();                  // vmem drained by compiler waitcnt @ barrier
  layer_body(t, s, rbase, hout + (size_t)s * AG * DD, ea,
             Wf, bfv, Ws, bsv, R1, agg2, stats2);
}

// K3: out = relu(BN2(agg2) + h), in place on d_out (holds h).
__global__ __launch_bounds__(256) void k_norm(
    const float* __restrict__ agg, const double* __restrict__ stats,
    const float* __restrict__ gmv, const float* __restrict__ btv,
    float* __restrict__ outp)
{
  __shared__ __align__(16) float sc[DD];
  __shared__ __align__(16) float sh[DD];
  const int t = threadIdx.x;
  if (t < DD) {
    double mu  = stats[t] * (1.0 / NN);
    double var = stats[DD + t] * (1.0 / NN) - mu * mu;
    float rs = (float)(1.0 / sqrt(var + BN_EPS_SCALED));
    float g  = gmv[t] * rs;
    sc[t] = g;
    sh[t] = btv[t] - (float)mu * g;
  }
  __syncthreads();
  const int idx = blockIdx.x * 256 + t;          // f4 index
  const int c   = (idx * 4) & (DD - 1);
  f4 a = ((const f4*)agg)[idx];
  f4 h = ((const f4*)outp)[idx];
  f4 r = a * (*(const f4*)&sc[c]) + (*(const f4*)&sh[c]) + h;
#pragma unroll
  for (int k = 0; k < 4; ++k) r[k] = fmaxf(r[k], 0.0f);
  ((f4*)outp)[idx] = r;
}

extern "C" void kernel_launch(void* const* d_in, const int* in_sizes, int n_in,
                              void* d_out, int out_size, void* d_ws, size_t ws_size,
                              hipStream_t stream) {
  const float* x   = (const float*)d_in[0];
  // d_in[1] = edge_index: deterministic meshgrid structure, recomputed on device
  const float* ea  = (const float*)d_in[2];
  const float* Wf1 = (const float*)d_in[3];
  const float* bf1 = (const float*)d_in[4];
  const float* Ws1 = (const float*)d_in[5];
  const float* bs1 = (const float*)d_in[6];
  const float* gm1 = (const float*)d_in[7];
  const float* bt1 = (const float*)d_in[8];
  const float* Wf2 = (const float*)d_in[9];
  const float* bf2 = (const float*)d_in[10];
  const float* Ws2 = (const float*)d_in[11];
  const float* bs2 = (const float*)d_in[12];
  const float* gm2 = (const float*)d_in[13];
  const float* bt2 = (const float*)d_in[14];

  // ws layout: [0,2KB) stats (memset 0); agg1 @4KB (8MB); agg2 @4KB+8MB (8MB).
  // agg2 must be separate from agg1: each K2 half-block reads the sibling
  // half's agg1 rows in its prologue.
  double* stats = (double*)d_ws;
  float*  agg1  = (float*)((char*)d_ws + 4096);
  float*  agg2  = (float*)((char*)d_ws + 4096 + (size_t)NN * DD * 4);
  float*  outp  = (float*)d_out;                 // h after K2, out after K3

  hipMemsetAsync(d_ws, 0, 2048, stream);
  k_edge1<<<2 * NSAMP, 256, 0, stream>>>(x, ea, Wf1, bf1, Ws1, bs1, agg1, stats);
  k_edge2<<<2 * NSAMP, 256, 0, stream>>>(x, ea, Wf2, bf2, Ws2, bs2,
                                         stats, gm1, bt1, outp, agg1, agg2,
                                         stats + 128);
  k_norm<<<NN * DD / 4 / 256, 256, 0, stream>>>(agg2, stats + 128, gm2, bt2, outp);
}

// Round 13
// 294.647 us; speedup vs baseline: 1.4736x; 1.1148x over previous
//
#include <hip/hip_runtime.h>

// AgentGnn: 2x CGConv(D=64) on 1024 disjoint fully-connected 32-node blocks.
// Round 13 = round 10 with the merge bug fixed: edge_attr was scaled by L2E
// at staging AND the edge weight rows were scaled by L2E (round-6 + round-9
// conventions combined) -> edge term got L2E^2, absmax 0.3125 (marginal fail).
// Now edge_attr is staged UNSCALED; the L2E lives in the weight rows only.
// Structure: 2048 half-sample blocks (16 dst x 16 ch-groups, 4 ch/thread),
// xb LDS stages x/h for the gpasses then is reused for edge_attr,
// LDS total 25088B -> 6 blocks/CU potential. Math: z@W split, exp2-domain
// gate (G outputs scaled by log2e, softplus ln2 dropped, BN eps scaled by
// L2E^2 -> exactly equivalent to the reference in real arithmetic).

#define NSAMP 1024
#define AG 32
#define DD 64
#define EPB 992          // edges per sample = 32*31
#define NN 32768
#define R1S 132          // padded row stride (rows start at banks 0/4/8/12...)

typedef float f4 __attribute__((ext_vector_type(4)));
typedef float f2 __attribute__((ext_vector_type(2)));

#define L2E 1.44269504088896340736f
// rsqrt(c^2 v + c^2 eps)*c == rsqrt(v+eps), c = L2E
#define BN_EPS_SCALED (1e-5 * (double)L2E * (double)L2E)

// acc += sigmoid(mf)*softplus(ms)/ln2; mf,ms pre-scaled by log2e.
// __builtin_amdgcn_logf == v_log_f32 == log2: log2(1+2^ms)=max(ms,0)+log2(1+2^-|ms|).
__device__ __forceinline__ void gacc(f4& acc, const f4 mf, const f4 ms) {
#pragma unroll
  for (int k = 0; k < 4; ++k) {
    float sig = __builtin_amdgcn_rcpf(1.0f + __builtin_amdgcn_exp2f(-mf[k]));
    float sp  = fmaxf(ms[k], 0.0f)
              + __builtin_amdgcn_logf(1.0f + __builtin_amdgcn_exp2f(-fabsf(ms[k])));
    acc[k] += sig * sp;   // v_fmac
  }
}

// G half-pass reading node features from LDS xb (32x64, unscaled).
// SRC=0: W rows [0:64] (dst) + bias; own-half rows rbase..rbase+16 -> local 0..16.
// SRC=1: W rows [64:128] (src), all 32 rows. Output scaled by L2E.
template <int SRC>
__device__ __forceinline__ void gpass(const float* __restrict__ Wf,
                                      const float* __restrict__ bfv,
                                      const float* __restrict__ Ws,
                                      const float* __restrict__ bsv,
                                      const float* xb, float* R1,
                                      int t, int rbase) {
  const int tx = t & 31, ty = t >> 5;          // 8 row groups
  const int q = tx >> 4;                        // 0: f-gate, 1: s-gate
  const int cc0 = (tx & 15) * 4;
  const float* wbase = (q ? Ws : Wf) + SRC * (64 * 64) + cc0;
  constexpr int RPT = (SRC == 0) ? 2 : 4;       // rows per thread
  f4 acc[RPT];
  if constexpr (SRC == 0) {
    const float* bv = q ? bsv : bfv;
    f4 b = *(const f4*)(bv + cc0);
#pragma unroll
    for (int r = 0; r < RPT; ++r) acc[r] = b;
  } else {
    f4 z = {0.f, 0.f, 0.f, 0.f};
#pragma unroll
    for (int r = 0; r < RPT; ++r) acc[r] = z;
  }
#pragma unroll 4
  for (int k4 = 0; k4 < 16; ++k4) {
    const float* wp = wbase + k4 * 256;         // 4 weight rows, coalesced f4
    f4 w0 = *(const f4*)(wp);
    f4 w1 = *(const f4*)(wp + 64);
    f4 w2 = *(const f4*)(wp + 128);
    f4 w3 = *(const f4*)(wp + 192);
#pragma unroll
    for (int r = 0; r < RPT; ++r) {
      const int row = (SRC == 0) ? (rbase + ty * RPT + r) : (ty * RPT + r);
      f4 xv = *(const f4*)&xb[row * 64 + k4 * 4];   // LDS broadcast (2 addrs/wave)
      acc[r] += xv.x * w0 + xv.y * w1 + xv.z * w2 + xv.w * w3;
    }
  }
#pragma unroll
  for (int r = 0; r < RPT; ++r)
    *(f4*)&R1[(ty * RPT + r) * R1S + q * 64 + cc0] = acc[r] * L2E;
}

// One layer for a half-sample block. Pre: xb holds the 32x64 node features
// (x or h, UNSCALED), threads synced. Stages edges into xb (overwrite!).
__device__ __forceinline__ void layer_body(
    int t, int s, int rbase, const float* __restrict__ ea,
    const float* __restrict__ Wf, const float* __restrict__ bfv,
    const float* __restrict__ Ws, const float* __restrict__ bsv,
    float* xb, float* R1, float* __restrict__ agg, double* __restrict__ stats)
{
  gpass<0>(Wf, bfv, Ws, bsv, xb, R1, t, rbase);         // own-half [Af|As]
  __syncthreads();
  const int il = t >> 4, c0 = (t & 15) * 4;
  f4 af  = *(const f4*)&R1[il * R1S + c0];
  f4 as_ = *(const f4*)&R1[il * R1S + 64 + c0];
  __syncthreads();                                       // reads done
  gpass<1>(Wf, bfv, Ws, bsv, xb, R1, t, 0);              // all-32 [Bf|Bs]

  // Edge-dim weight rows carry the ONLY L2E for the edge term
  // (edge_attr is staged UNSCALED below — round-12 bug was scaling both).
  f4 wf0 = *(const f4*)(Wf + 128 * 64 + c0) * L2E;
  f4 wf1 = *(const f4*)(Wf + 129 * 64 + c0) * L2E;
  f4 ws0 = *(const f4*)(Ws + 128 * 64 + c0) * L2E;
  f4 ws1 = *(const f4*)(Ws + 129 * 64 + c0) * L2E;
  __syncthreads();                                       // gpass1 xb reads done

  { // stage edge_attr UNSCALED into xb (node features consumed)
    const f2* esrc = ((const f2*)ea) + (size_t)s * EPB;
    f2* ed = (f2*)xb;
    for (int u = t; u < EPB; u += 256) ed[u] = esrc[u];
  }
  __syncthreads();

  const int i = rbase + il;                              // own dst node
  f4 acc = {0.f, 0.f, 0.f, 0.f};
  for (int jj = 0; jj < 31; ++jj) {                      // skip diagonal
    const int ge = (jj >= i) ? 1 : 0;
    const int j  = jj + ge;
    const int e  = j * 31 + i - 1 + ge;                  // src-major edge id
    f2 eav = *(const f2*)&xb[e * 2];                     // LDS, 4 addrs/wave
    f4 bf_ = *(const f4*)&R1[j * R1S + c0];              // j uniform: broadcast
    f4 bs_ = *(const f4*)&R1[j * R1S + 64 + c0];
    f4 mf = af  + bf_ + eav.x * wf0 + eav.y * wf1;
    f4 ms = as_ + bs_ + eav.x * ws0 + eav.y * ws1;
    gacc(acc, mf, ms);
  }
  *(f4*)(agg + ((size_t)s * AG + i) * DD + c0) = acc;

  // BN stats: shfl-reduce 4 same-channel lanes (t^16/t^32 vary il, keep c0),
  // then LDS accumulate, then one double atomic per channel-stat.
  f4 s1 = acc, sq = acc * acc;
#pragma unroll
  for (int k = 0; k < 4; ++k) {
    s1[k] += __shfl_xor(s1[k], 16); sq[k] += __shfl_xor(sq[k], 16);
    s1[k] += __shfl_xor(s1[k], 32); sq[k] += __shfl_xor(sq[k], 32);
  }
  __syncthreads();                                       // R1 loop reads done
  if (t < 128) R1[t] = 0.0f;
  __syncthreads();
  if ((t & 63) < 16) {
#pragma unroll
    for (int k = 0; k < 4; ++k) {
      atomicAdd(&R1[c0 + k],      s1[k]);
      atomicAdd(&R1[64 + c0 + k], sq[k]);
    }
  }
  __syncthreads();
  if (t < 128) atomicAdd(&stats[t], (double)R1[t]);
}

// K1: layer-1 edge phase (half-sample blocks, grid 2048).
__global__ __launch_bounds__(256, 4) void k_edge1(
    const float* __restrict__ x, const float* __restrict__ ea,
    const float* __restrict__ Wf, const float* __restrict__ bfv,
    const float* __restrict__ Ws, const float* __restrict__ bsv,
    float* __restrict__ agg, double* __restrict__ stats)
{
  __shared__ __align__(16) float xb[2048];       // x, then edge_attr
  __shared__ __align__(16) float R1[32 * R1S];
  const int t = threadIdx.x, b = blockIdx.x;
  const int s = b >> 1, rbase = (b & 1) * 16;
  { // stage full sample x (gpass<1> needs all 32 rows)
    const f4* src = (const f4*)(x + (size_t)s * AG * DD);
    f4* dst = (f4*)xb;
    dst[t]       = src[t];
    dst[t + 256] = src[t + 256];
  }
  __syncthreads();
  layer_body(t, s, rbase, ea, Wf, bfv, Ws, bsv, xb, R1, agg, stats);
}

// K2: BN1-apply+residual+relu -> h for all 32 rows (into LDS xb + d_out;
// duplicate identical global writes from the 2 siblings are race-safe),
// then layer-2 edge. agg2 separate from agg1 (sibling reads agg1 late).
__global__ __launch_bounds__(256, 4) void k_edge2(
    const float* __restrict__ x, const float* __restrict__ ea,
    const float* __restrict__ Wf, const float* __restrict__ bfv,
    const float* __restrict__ Ws, const float* __restrict__ bsv,
    const double* __restrict__ stats1, const float* __restrict__ gmv,
    const float* __restrict__ btv, float* __restrict__ hout,
    const float* __restrict__ agg1, float* __restrict__ agg2,
    double* __restrict__ stats2)
{
  __shared__ __align__(16) float xb[2048];       // h, then edge_attr
  __shared__ __align__(16) float R1[32 * R1S];
  const int t = threadIdx.x, b = blockIdx.x;
  const int s = b >> 1, rbase = (b & 1) * 16;

  if (t < 64) {                     // BN1 scale/shift (redundant per block)
    double mu  = stats1[t] * (1.0 / NN);
    double var = stats1[64 + t] * (1.0 / NN) - mu * mu;
    float rs = (float)(1.0 / sqrt(var + BN_EPS_SCALED));
    float g  = gmv[t] * rs;
    R1[t]      = g;
    R1[64 + t] = btv[t] - (float)mu * g;
  }
  __syncthreads();
  {                                 // h = relu(BN1(agg1)+x), all 32 rows
    const int row = t >> 3, cc = (t & 7) * 8;
    const size_t base = ((size_t)s * AG + row) * DD + cc;
    f4 sc0 = *(const f4*)&R1[cc],      sc1 = *(const f4*)&R1[cc + 4];
    f4 sh0 = *(const f4*)&R1[64 + cc], sh1 = *(const f4*)&R1[64 + cc + 4];
    f4 a0 = *(const f4*)(agg1 + base), a1 = *(const f4*)(agg1 + base + 4);
    f4 x0 = *(const f4*)(x + base),    x1 = *(const f4*)(x + base + 4);
    f4 h0 = a0 * sc0 + sh0 + x0;
    f4 h1 = a1 * sc1 + sh1 + x1;
#pragma unroll
    for (int k = 0; k < 4; ++k) { h0[k] = fmaxf(h0[k], 0.f); h1[k] = fmaxf(h1[k], 0.f); }
    *(f4*)(hout + base)     = h0;   // for K3's residual (identical dup bytes)
    *(f4*)(hout + base + 4) = h1;
    *(f4*)&xb[row * DD + cc]     = h0;  // layer-2 input, stays in LDS
    *(f4*)&xb[row * DD + cc + 4] = h1;
  }
  __syncthreads();                  // h visible; R1 sc/sh reads done
  layer_body(t, s, rbase, ea, Wf, bfv, Ws, bsv, xb, R1, agg2, stats2);
}

// K3: out = relu(BN2(agg2) + h), in place on d_out (holds h).
__global__ __launch_bounds__(256) void k_norm(
    const float* __restrict__ agg, const double* __restrict__ stats,
    const float* __restrict__ gmv, const float* __restrict__ btv,
    float* __restrict__ outp)
{
  __shared__ __align__(16) float sc[DD];
  __shared__ __align__(16) float sh[DD];
  const int t = threadIdx.x;
  if (t < DD) {
    double mu  = stats[t] * (1.0 / NN);
    double var = stats[DD + t] * (1.0 / NN) - mu * mu;
    float rs = (float)(1.0 / sqrt(var + BN_EPS_SCALED));
    float g  = gmv[t] * rs;
    sc[t] = g;
    sh[t] = btv[t] - (float)mu * g;
  }
  __syncthreads();
  const int idx = blockIdx.x * 256 + t;          // f4 index
  const int c   = (idx * 4) & (DD - 1);
  f4 a = ((const f4*)agg)[idx];
  f4 h = ((const f4*)outp)[idx];
  f4 r = a * (*(const f4*)&sc[c]) + (*(const f4*)&sh[c]) + h;
#pragma unroll
  for (int k = 0; k < 4; ++k) r[k] = fmaxf(r[k], 0.0f);
  ((f4*)outp)[idx] = r;
}

extern "C" void kernel_launch(void* const* d_in, const int* in_sizes, int n_in,
                              void* d_out, int out_size, void* d_ws, size_t ws_size,
                              hipStream_t stream) {
  const float* x   = (const float*)d_in[0];
  // d_in[1] = edge_index: deterministic meshgrid structure, recomputed on device
  const float* ea  = (const float*)d_in[2];
  const float* Wf1 = (const float*)d_in[3];
  const float* bf1 = (const float*)d_in[4];
  const float* Ws1 = (const float*)d_in[5];
  const float* bs1 = (const float*)d_in[6];
  const float* gm1 = (const float*)d_in[7];
  const float* bt1 = (const float*)d_in[8];
  const float* Wf2 = (const float*)d_in[9];
  const float* bf2 = (const float*)d_in[10];
  const float* Ws2 = (const float*)d_in[11];
  const float* bs2 = (const float*)d_in[12];
  const float* gm2 = (const float*)d_in[13];
  const float* bt2 = (const float*)d_in[14];

  // ws layout: [0,2KB) stats (memset 0); agg1 @4KB (8MB); agg2 @4KB+8MB (8MB).
  double* stats = (double*)d_ws;
  float*  agg1  = (float*)((char*)d_ws + 4096);
  float*  agg2  = (float*)((char*)d_ws + 4096 + (size_t)NN * DD * 4);
  float*  outp  = (float*)d_out;                 // h after K2, out after K3

  hipMemsetAsync(d_ws, 0, 2048, stream);
  k_edge1<<<2 * NSAMP, 256, 0, stream>>>(x, ea, Wf1, bf1, Ws1, bs1, agg1, stats);
  k_edge2<<<2 * NSAMP, 256, 0, stream>>>(x, ea, Wf2, bf2, Ws2, bs2,
                                         stats, gm1, bt1, outp, agg1, agg2,
                                         stats + 128);
  k_norm<<<NN * DD / 4 / 256, 256, 0, stream>>>(agg2, stats + 128, gm2, bt2, outp);
}

// Round 14
// 248.861 us; speedup vs baseline: 1.7447x; 1.1840x over previous
//
#include <hip/hip_runtime.h>

// AgentGnn: 2x CGConv(D=64) on 1024 disjoint fully-connected 32-node blocks.
// Round 14: full-sample blocks of 512 THREADS (8 waves). Round 13 proved the
// half-sample split costs 1.5x G-FLOPs + 2x staging for only +6% occupancy.
// Here: grid 1024 (one sample/block, zero duplicated work, round-6 FLOPs),
// but 8 waves/block x 4 blocks/CU = 32 waves/CU (100% of slots; round 6 was
// grid-capped at 50%). LDS stays slim (25088B) via the two-pass G: pass0
// [Af|As] -> regs, pass1 [Bf|Bs] -> LDS (R1, stride 132). 4 ch/thread body
// measured at exactly 64 VGPR in rounds 9/13 -> 8 waves/SIMD feasible.
// Math (unchanged, verified r13): z@W split; exp2-domain gate — G outputs
// and edge WEIGHT ROWS carry the single L2E (edge_attr staged UNSCALED);
// softplus ln2 dropped; BN eps scaled by L2E^2 -> exact in real arithmetic.

#define NSAMP 1024
#define AG 32
#define DD 64
#define EPB 992          // edges per sample = 32*31
#define NN 32768
#define R1S 132          // padded row stride

typedef float f4 __attribute__((ext_vector_type(4)));
typedef float f2 __attribute__((ext_vector_type(2)));

#define L2E 1.44269504088896340736f
// rsqrt(c^2 v + c^2 eps)*c == rsqrt(v+eps), c = L2E
#define BN_EPS_SCALED (1e-5 * (double)L2E * (double)L2E)

// acc += sigmoid(mf)*softplus(ms)/ln2; mf,ms pre-scaled by log2e.
// __builtin_amdgcn_logf == v_log_f32 == log2: log2(1+2^ms)=max(ms,0)+log2(1+2^-|ms|).
__device__ __forceinline__ void gacc(f4& acc, const f4 mf, const f4 ms) {
#pragma unroll
  for (int k = 0; k < 4; ++k) {
    float sig = __builtin_amdgcn_rcpf(1.0f + __builtin_amdgcn_exp2f(-mf[k]));
    float sp  = fmaxf(ms[k], 0.0f)
              + __builtin_amdgcn_logf(1.0f + __builtin_amdgcn_exp2f(-fabsf(ms[k])));
    acc[k] += sig * sp;   // v_fmac
  }
}

// G half-pass, 512 threads, all 32 rows x 128 cols ([*f|*s] for one W half).
// SRC=0: W rows [0:64] (dst) + bias. SRC=1: W rows [64:128] (src), no bias.
// Output scaled by L2E. Thread: (tx&15)*4 = col group, tx>>4 = f/s quadrant,
// ty = t>>5 in 0..15, 2 rows each.
template <int SRC>
__device__ __forceinline__ void gpass(const float* __restrict__ Wf,
                                      const float* __restrict__ bfv,
                                      const float* __restrict__ Ws,
                                      const float* __restrict__ bsv,
                                      const float* xb, float* R1, int t) {
  const int tx = t & 31, ty = t >> 5;          // 16 row groups x 2 rows
  const int q = tx >> 4;                        // 0: f-gate, 1: s-gate
  const int cc0 = (tx & 15) * 4;
  const float* wbase = (q ? Ws : Wf) + SRC * (64 * 64) + cc0;
  f4 acc0, acc1;
  if constexpr (SRC == 0) {
    const float* bv = q ? bsv : bfv;
    f4 b = *(const f4*)(bv + cc0);
    acc0 = b; acc1 = b;
  } else {
    f4 z = {0.f, 0.f, 0.f, 0.f};
    acc0 = z; acc1 = z;
  }
  const int r0 = ty * 2;
#pragma unroll 4
  for (int k4 = 0; k4 < 16; ++k4) {
    const float* wp = wbase + k4 * 256;         // 4 weight rows, coalesced f4
    f4 w0 = *(const f4*)(wp);
    f4 w1 = *(const f4*)(wp + 64);
    f4 w2 = *(const f4*)(wp + 128);
    f4 w3 = *(const f4*)(wp + 192);
    f4 xv0 = *(const f4*)&xb[r0 * 64 + k4 * 4];       // 2 addrs/wave: free
    f4 xv1 = *(const f4*)&xb[(r0 + 1) * 64 + k4 * 4];
    acc0 += xv0.x * w0 + xv0.y * w1 + xv0.z * w2 + xv0.w * w3;
    acc1 += xv1.x * w0 + xv1.y * w1 + xv1.z * w2 + xv1.w * w3;
  }
  *(f4*)&R1[r0 * R1S + q * 64 + cc0]       = acc0 * L2E;
  *(f4*)&R1[(r0 + 1) * R1S + q * 64 + cc0] = acc1 * L2E;
}

// One layer for a full-sample block (512 threads). Pre: xb holds the 32x64
// node features (UNSCALED), synced. Stages edges into xb (overwrite!).
__device__ __forceinline__ void layer_body(
    int t, int s, const float* __restrict__ ea,
    const float* __restrict__ Wf, const float* __restrict__ bfv,
    const float* __restrict__ Ws, const float* __restrict__ bsv,
    float* xb, float* R1, float* __restrict__ agg, double* __restrict__ stats)
{
  gpass<0>(Wf, bfv, Ws, bsv, xb, R1, t);                // [Af|As] all 32 rows
  __syncthreads();
  const int i = t >> 4, c0 = (t & 15) * 4;              // own node, 4 channels
  f4 af  = *(const f4*)&R1[i * R1S + c0];
  f4 as_ = *(const f4*)&R1[i * R1S + 64 + c0];
  __syncthreads();                                      // reads done
  gpass<1>(Wf, bfv, Ws, bsv, xb, R1, t);                // [Bf|Bs] all 32 rows

  // Edge-dim weight rows carry the ONLY L2E for the edge term.
  f4 wf0 = *(const f4*)(Wf + 128 * 64 + c0) * L2E;
  f4 wf1 = *(const f4*)(Wf + 129 * 64 + c0) * L2E;
  f4 ws0 = *(const f4*)(Ws + 128 * 64 + c0) * L2E;
  f4 ws1 = *(const f4*)(Ws + 129 * 64 + c0) * L2E;
  __syncthreads();                                      // gpass1 xb reads done

  { // stage edge_attr UNSCALED into xb (node features consumed)
    const f2* esrc = ((const f2*)ea) + (size_t)s * EPB;
    f2* ed = (f2*)xb;
    for (int u = t; u < EPB; u += 512) ed[u] = esrc[u];
  }
  __syncthreads();

  f4 acc = {0.f, 0.f, 0.f, 0.f};
  for (int jj = 0; jj < 31; ++jj) {                     // skip diagonal
    const int ge = (jj >= i) ? 1 : 0;
    const int j  = jj + ge;
    const int e  = j * 31 + i - 1 + ge;                 // src-major edge id
    f2 eav = *(const f2*)&xb[e * 2];                    // LDS
    f4 bf_ = *(const f4*)&R1[j * R1S + c0];             // j uniform: broadcast
    f4 bs_ = *(const f4*)&R1[j * R1S + 64 + c0];
    f4 mf = af  + bf_ + eav.x * wf0 + eav.y * wf1;
    f4 ms = as_ + bs_ + eav.x * ws0 + eav.y * ws1;
    gacc(acc, mf, ms);
  }
  *(f4*)(agg + ((size_t)s * AG + i) * DD + c0) = acc;

  // BN stats: shfl-reduce the wave's 4 same-channel nodes (t^16, t^32),
  // then LDS accumulate (8 waves x 16 lanes), one double atomic per stat.
  f4 s1 = acc, sq = acc * acc;
#pragma unroll
  for (int k = 0; k < 4; ++k) {
    s1[k] += __shfl_xor(s1[k], 16); sq[k] += __shfl_xor(sq[k], 16);
    s1[k] += __shfl_xor(s1[k], 32); sq[k] += __shfl_xor(sq[k], 32);
  }
  __syncthreads();                                      // R1 loop reads done
  if (t < 128) R1[t] = 0.0f;
  __syncthreads();
  if ((t & 63) < 16) {
#pragma unroll
    for (int k = 0; k < 4; ++k) {
      atomicAdd(&R1[c0 + k],      s1[k]);
      atomicAdd(&R1[64 + c0 + k], sq[k]);
    }
  }
  __syncthreads();
  if (t < 128) atomicAdd(&stats[t], (double)R1[t]);
}

// K1: layer-1 edge phase. Grid 1024 x 512 threads.
__global__ __launch_bounds__(512, 4) void k_edge1(
    const float* __restrict__ x, const float* __restrict__ ea,
    const float* __restrict__ Wf, const float* __restrict__ bfv,
    const float* __restrict__ Ws, const float* __restrict__ bsv,
    float* __restrict__ agg, double* __restrict__ stats)
{
  __shared__ __align__(16) float xb[2048];       // x, then edge_attr
  __shared__ __align__(16) float R1[32 * R1S];
  const int t = threadIdx.x, s = blockIdx.x;
  ((f4*)xb)[t] = ((const f4*)(x + (size_t)s * AG * DD))[t];   // 512 f4
  __syncthreads();
  layer_body(t, s, ea, Wf, bfv, Ws, bsv, xb, R1, agg, stats);
}

// K2: BN1-apply+residual+relu -> h (to LDS xb + d_out), then layer-2 edge.
// One block per sample: agg is read (prologue) then overwritten (layer_body)
// by the SAME block only -> one agg buffer suffices.
__global__ __launch_bounds__(512, 4) void k_edge2(
    const float* __restrict__ x, const float* __restrict__ ea,
    const float* __restrict__ Wf, const float* __restrict__ bfv,
    const float* __restrict__ Ws, const float* __restrict__ bsv,
    const double* __restrict__ stats1, const float* __restrict__ gmv,
    const float* __restrict__ btv, float* __restrict__ hout,
    float* __restrict__ agg, double* __restrict__ stats2)
{
  __shared__ __align__(16) float xb[2048];       // h, then edge_attr
  __shared__ __align__(16) float R1[32 * R1S];
  const int t = threadIdx.x, s = blockIdx.x;

  if (t < 64) {                     // BN1 scale/shift from global stats
    double mu  = stats1[t] * (1.0 / NN);
    double var = stats1[64 + t] * (1.0 / NN) - mu * mu;
    float rs = (float)(1.0 / sqrt(var + BN_EPS_SCALED));
    float g  = gmv[t] * rs;
    R1[t]      = g;
    R1[64 + t] = btv[t] - (float)mu * g;
  }
  __syncthreads();
  {                                 // h = relu(BN1(agg)+x), 1 f4 per thread
    const int row = t >> 4, cc = (t & 15) * 4;
    const size_t base = ((size_t)s * AG + row) * DD + cc;
    f4 a  = *(const f4*)(agg + base);
    f4 x0 = *(const f4*)(x + base);
    f4 h = a * (*(const f4*)&R1[cc]) + (*(const f4*)&R1[64 + cc]) + x0;
#pragma unroll
    for (int k = 0; k < 4; ++k) h[k] = fmaxf(h[k], 0.f);
    *(f4*)(hout + base) = h;        // for K3's residual
    *(f4*)&xb[row * DD + cc] = h;   // layer-2 input, stays in LDS
  }
  __syncthreads();                  // h visible; sc/sh reads done
  layer_body(t, s, ea, Wf, bfv, Ws, bsv, xb, R1, agg, stats2);
}

// K3: out = relu(BN2(agg) + h), in place on d_out (holds h).
__global__ __launch_bounds__(256) void k_norm(
    const float* __restrict__ agg, const double* __restrict__ stats,
    const float* __restrict__ gmv, const float* __restrict__ btv,
    float* __restrict__ outp)
{
  __shared__ __align__(16) float sc[DD];
  __shared__ __align__(16) float sh[DD];
  const int t = threadIdx.x;
  if (t < DD) {
    double mu  = stats[t] * (1.0 / NN);
    double var = stats[DD + t] * (1.0 / NN) - mu * mu;
    float rs = (float)(1.0 / sqrt(var + BN_EPS_SCALED));
    float g  = gmv[t] * rs;
    sc[t] = g;
    sh[t] = btv[t] - (float)mu * g;
  }
  __syncthreads();
  const int idx = blockIdx.x * 256 + t;          // f4 index
  const int c   = (idx * 4) & (DD - 1);
  f4 a = ((const f4*)agg)[idx];
  f4 h = ((const f4*)outp)[idx];
  f4 r = a * (*(const f4*)&sc[c]) + (*(const f4*)&sh[c]) + h;
#pragma unroll
  for (int k = 0; k < 4; ++k) r[k] = fmaxf(r[k], 0.0f);
  ((f4*)outp)[idx] = r;
}

extern "C" void kernel_launch(void* const* d_in, const int* in_sizes, int n_in,
                              void* d_out, int out_size, void* d_ws, size_t ws_size,
                              hipStream_t stream) {
  const float* x   = (const float*)d_in[0];
  // d_in[1] = edge_index: deterministic meshgrid structure, recomputed on device
  const float* ea  = (const float*)d_in[2];
  const float* Wf1 = (const float*)d_in[3];
  const float* bf1 = (const float*)d_in[4];
  const float* Ws1 = (const float*)d_in[5];
  const float* bs1 = (const float*)d_in[6];
  const float* gm1 = (const float*)d_in[7];
  const float* bt1 = (const float*)d_in[8];
  const float* Wf2 = (const float*)d_in[9];
  const float* bf2 = (const float*)d_in[10];
  const float* Ws2 = (const float*)d_in[11];
  const float* bs2 = (const float*)d_in[12];
  const float* gm2 = (const float*)d_in[13];
  const float* bt2 = (const float*)d_in[14];

  // ws layout: [0,2KB) stats (memset 0); agg @4KB (8MB, reused L1->L2).
  double* stats = (double*)d_ws;
  float*  agg   = (float*)((char*)d_ws + 4096);
  float*  outp  = (float*)d_out;                 // h after K2, out after K3

  hipMemsetAsync(d_ws, 0, 2048, stream);
  k_edge1<<<NSAMP, 512, 0, stream>>>(x, ea, Wf1, bf1, Ws1, bs1, agg, stats);
  k_edge2<<<NSAMP, 512, 0, stream>>>(x, ea, Wf2, bf2, Ws2, bs2,
                                     stats, gm1, bt1, outp, agg, stats + 128);
  k_norm<<<NN * DD / 4 / 256, 256, 0, stream>>>(agg, stats + 128, gm2, bt2, outp);
}